// Round 19
// baseline (953.716 us; speedup 1.0000x reference)
//
#include <hip/hip_runtime.h>

#define NN 10000
#define STRD 10272   // bf16 panel/adjb row stride (elements)
#define FSPLIT 16    // gmmf K-slices
#define FSTEPS 20    // gmmf K-steps of 32
#define PSPLIT 16    // gmm2 K-slices
#define PSTEPS 20    // gmm2 K-steps of 32
#define FEAT 2048
#define HID 128
#define NCLS 64

typedef short s16x8 __attribute__((ext_vector_type(8)));
typedef float f32x4 __attribute__((ext_vector_type(4)));

static __device__ __forceinline__ unsigned short f2bf(float f) {
  unsigned int u = __float_as_uint(f);
  u += 0x7FFFu + ((u >> 16) & 1u);
  return (unsigned short)(u >> 16);
}

#define MFMA16(accv, av, bv) \
  (accv) = __builtin_amdgcn_mfma_f32_16x16x32_bf16((av), (bv), (accv), 0, 0, 0)

#define FENCE_ANCHOR() do { asm volatile("" ::: "memory"); __builtin_amdgcn_sched_barrier(0); } while (0)

__device__ __forceinline__ void vmwait(int n) {
  switch (n) {
    case 0: asm volatile("s_waitcnt vmcnt(0)" ::: "memory"); break;
    case 2: asm volatile("s_waitcnt vmcnt(2)" ::: "memory"); break;
    case 3: asm volatile("s_waitcnt vmcnt(3)" ::: "memory"); break;
    case 4: asm volatile("s_waitcnt vmcnt(4)" ::: "memory"); break;
    case 5: asm volatile("s_waitcnt vmcnt(5)" ::: "memory"); break;
    default: asm volatile("s_waitcnt vmcnt(6)" ::: "memory"); break;
  }
}

// Self-calibration of the MFMA C/D lane->(m,n) mapping (proved correct in R2).
__device__ __forceinline__ void calib_mn(int lane, int* cm, int* cn) {
  const int lr = lane & 15;
  const int lg = lane >> 4;
  s16x8 pa, pb;
#pragma unroll
  for (int j = 0; j < 8; ++j) { pa[j] = 0; pb[j] = 0; }
  if (lg == 0) {
    pa[0] = (short)f2bf(1.0f);
    pa[1] = (short)f2bf((float)(1 + lr));
    pb[0] = (short)f2bf((float)(128 * (1 + lr)));
    pb[1] = (short)f2bf(1.0f);
  }
  f32x4 acc;
#pragma unroll
  for (int j = 0; j < 4; ++j) acc[j] = 0.f;
  MFMA16(acc, pa, pb);
#pragma unroll
  for (int r = 0; r < 4; ++r) {
    const int v = (int)acc[r];
    cm[r] = (v & 127) - 1;
    cn[r] = (v >> 7) - 1;
  }
}

__global__ void zero_f32_kernel(float* __restrict__ p, int n) {
  int i = blockIdx.x * 256 + threadIdx.x;
  if (i < n) p[i] = 0.f;
}

// prep: transpose W1, W2 to bf16; zero pad columns of the 3 bf16 p-panels
__global__ void prep_kernel(const float* __restrict__ W1, const float* __restrict__ W2,
                            unsigned short* __restrict__ W1T, unsigned short* __restrict__ W2T,
                            unsigned short* __restrict__ HT, unsigned short* __restrict__ pA,
                            unsigned short* __restrict__ pB) {
  const int idx = blockIdx.x * 256 + threadIdx.x;
  if (idx < FEAT * HID) {
    const int k = idx / HID, c = idx % HID;
    W1T[(size_t)c * FEAT + k] = f2bf(W1[idx]);
  }
  if (idx < HID * NCLS) {
    const int k = idx / NCLS, c = idx % NCLS;
    W2T[(size_t)c * HID + k] = f2bf(W2[idx]);
  }
  if (idx < 3 * 64 * (STRD - NN)) {
    const int span = 64 * (STRD - NN);
    const int p = idx / span;
    const int rem = idx % span;
    const int c = rem / (STRD - NN);
    const int col = NN + rem % (STRD - NN);
    unsigned short* pan = (p == 0) ? HT : ((p == 1) ? pA : pB);
    pan[(size_t)c * STRD + col] = 0;
  }
}

// ---------------- MLP layer 1 ----------------
__global__ __launch_bounds__(256) void mlp1_kernel(
    const float* __restrict__ X, const unsigned short* __restrict__ W1T,
    const float* __restrict__ b1, unsigned short* __restrict__ H1) {
  __shared__ float red[4][16][HID];
  const int tid = threadIdx.x, wv = tid >> 6, lane = tid & 63;
  const int lr = lane & 15, lg = lane >> 4;
  const int r0 = blockIdx.x * 16;
  int cm[4], cn[4];
  calib_mn(lane, cm, cn);

  f32x4 acc[8];
#pragma unroll
  for (int t = 0; t < 8; ++t)
#pragma unroll
    for (int j = 0; j < 4; ++j) acc[t][j] = 0.f;

  for (int s = wv * 16; s < wv * 16 + 16; ++s) {
    const int kg = s * 32 + 8 * lg;
    const float* px = X + (size_t)(r0 + lr) * FEAT + kg;
    const float4 xa = *(const float4*)(px);
    const float4 xb = *(const float4*)(px + 4);
    s16x8 af;
    af[0] = (short)f2bf(xa.x); af[1] = (short)f2bf(xa.y);
    af[2] = (short)f2bf(xa.z); af[3] = (short)f2bf(xa.w);
    af[4] = (short)f2bf(xb.x); af[5] = (short)f2bf(xb.y);
    af[6] = (short)f2bf(xb.z); af[7] = (short)f2bf(xb.w);
#pragma unroll
    for (int t = 0; t < 8; ++t) {
      const s16x8 bf = *(const s16x8*)(W1T + (size_t)(16 * t + lr) * FEAT + kg);
      MFMA16(acc[t], af, bf);
    }
  }
#pragma unroll
  for (int t = 0; t < 8; ++t)
#pragma unroll
    for (int r = 0; r < 4; ++r)
      red[wv][cm[r]][16 * t + cn[r]] = acc[t][r];
  __syncthreads();

  const int row = tid >> 4;
  const int c0 = (tid & 15) * 8;
  s16x8 hv;
#pragma unroll
  for (int j = 0; j < 8; ++j) {
    float v = red[0][row][c0 + j] + red[1][row][c0 + j] +
              red[2][row][c0 + j] + red[3][row][c0 + j] + b1[c0 + j];
    v = fmaxf(v, 0.f);
    hv[j] = (short)f2bf(v);
  }
  *(s16x8*)(H1 + (size_t)(r0 + row) * HID + c0) = hv;
}

// ---------------- MLP layer 2 -> HT (bf16 64 x STRD) + out init ----------------
__global__ __launch_bounds__(256) void mlp2_kernel(
    const unsigned short* __restrict__ H1, const unsigned short* __restrict__ W2T,
    const float* __restrict__ b2, const float* __restrict__ comb,
    unsigned short* __restrict__ HT, float* __restrict__ out) {
  __shared__ float red[4][16][NCLS];
  const int tid = threadIdx.x, wv = tid >> 6, lane = tid & 63;
  const int lr = lane & 15, lg = lane >> 4;
  const int r0 = blockIdx.x * 16;
  int cm[4], cn[4];
  calib_mn(lane, cm, cn);

  f32x4 acc[4];
#pragma unroll
  for (int t = 0; t < 4; ++t)
#pragma unroll
    for (int j = 0; j < 4; ++j) acc[t][j] = 0.f;

  const int kg = wv * 32 + 8 * lg;
  const s16x8 af = *(const s16x8*)(H1 + (size_t)(r0 + lr) * HID + kg);
#pragma unroll
  for (int t = 0; t < 4; ++t) {
    const s16x8 bf = *(const s16x8*)(W2T + (size_t)(16 * t + lr) * HID + kg);
    MFMA16(acc[t], af, bf);
  }
#pragma unroll
  for (int t = 0; t < 4; ++t)
#pragma unroll
    for (int r = 0; r < 4; ++r)
      red[wv][cm[r]][16 * t + cn[r]] = acc[t][r];
  __syncthreads();

  const int row = tid >> 4;
  const int c4 = (tid & 15) * 4;
#pragma unroll
  for (int j = 0; j < 4; ++j) {
    const int c = c4 + j;
    const float v = red[0][row][c] + red[1][row][c] + red[2][row][c] + red[3][row][c] + b2[c];
    out[(size_t)(r0 + row) * NCLS + c] = comb[2 * NCLS + c] * v;
    HT[(size_t)c * STRD + r0 + row] = f2bf(v);
  }
}

// ================ gmm2: bf16 power pass — M=128, 3-buf counted-vmcnt ================
// grid (79, PSPLIT=16). LDS 3 x 12KB (A 128x32 bf16 8KB + B 64x32 bf16 4KB).
// 3 loads/wave/stage -> waits 6/3/0 (gmmf-proven scheme). Swizzle f(x) = (x>>1)&3.
__global__ __launch_bounds__(256) void gmm2_kernel(
    const unsigned short* __restrict__ Ab, const unsigned short* __restrict__ BT,
    float* __restrict__ Yf) {
  __shared__ unsigned char lds[3][12288];
  const int tid = threadIdx.x, wv = tid >> 6, lane = tid & 63;
  const int lr = lane & 15, lg = lane >> 4;
  const int r0 = blockIdx.x * 128;
  const int s0 = blockIdx.y * PSTEPS;
  int cm[4], cn[4];
  calib_mn(lane, cm, cn);

  f32x4 acc0[4], acc1[4];
#pragma unroll
  for (int t = 0; t < 4; ++t)
#pragma unroll
    for (int j = 0; j < 4; ++j) { acc0[t][j] = 0.f; acc1[t][j] = 0.f; }

  auto stage = [&](int b, int s) {
    const int k0 = s * 32;
#pragma unroll
    for (int i = 0; i < 2; ++i) {  // A: 512 16B-units (4/row, 128 rows)
      const int U = i * 256 + wv * 64 + lane;
      const int row = U >> 2, slot = U & 3;
      const int chunk = slot ^ ((row >> 1) & 3);
      const int gr = (r0 + row < NN) ? (r0 + row) : (NN - 1);
      __builtin_amdgcn_global_load_lds(Ab + (size_t)gr * STRD + k0 + chunk * 8,
                                       (void*)&lds[b][(i * 256 + wv * 64) * 16], 16, 0, 0);
    }
    {  // B: 256 16B-units (4/col)
      const int V = wv * 64 + lane;
      const int col = V >> 2, slot = V & 3;
      const int chunk = slot ^ ((col >> 1) & 3);
      __builtin_amdgcn_global_load_lds(BT + (size_t)col * STRD + k0 + chunk * 8,
                                       (void*)&lds[b][8192 + wv * 1024], 16, 0, 0);
    }
  };

  stage(0, s0); stage(1, s0 + 1); stage(2, s0 + 2);

  int bi = 0;
  for (int u = 0; u < PSTEPS; ++u) {
    if (u + 2 < PSTEPS)      vmwait(6);
    else if (u + 1 < PSTEPS) vmwait(3);
    else                     vmwait(0);
    __builtin_amdgcn_sched_barrier(0);
    __builtin_amdgcn_s_barrier();  // all waves' stage-u DMA landed
    FENCE_ANCHOR();
    {
      const unsigned char* L = lds[bi];
      const int row0 = wv * 32 + lr;
      const int row1 = row0 + 16;
      const s16x8 a0 = *(const s16x8*)(L + row0 * 64 + ((lg ^ ((row0 >> 1) & 3)) << 4));
      const s16x8 a1 = *(const s16x8*)(L + row1 * 64 + ((lg ^ ((row1 >> 1) & 3)) << 4));
#pragma unroll
      for (int t = 0; t < 4; ++t) {
        const int col = t * 16 + lr;
        const s16x8 bf = *(const s16x8*)(L + 8192 + col * 64 + ((lg ^ ((col >> 1) & 3)) << 4));
        MFMA16(acc0[t], a0, bf);
        MFMA16(acc1[t], a1, bf);
      }
    }
    asm volatile("s_waitcnt lgkmcnt(0)" ::: "memory");  // my ds_reads done
    __builtin_amdgcn_sched_barrier(0);
    __builtin_amdgcn_s_barrier();  // all waves done reading buf bi
    FENCE_ANCHOR();
    if (u + 3 < PSTEPS) stage(bi, s0 + u + 3);  // loads fly across barriers
    bi = (bi == 2) ? 0 : bi + 1;
  }

#pragma unroll
  for (int t = 0; t < 4; ++t) {
#pragma unroll
    for (int q = 0; q < 4; ++q) {
      const int c = 16 * t + cn[q];
      int r = r0 + wv * 32 + cm[q];
      if (r < NN) atomicAdd(&Yf[(size_t)r * NCLS + c], acc0[t][q]);
      r += 16;
      if (r < NN) atomicAdd(&Yf[(size_t)r * NCLS + c], acc1[t][q]);
    }
  }
}

// ================ gmmf: filters — f32 A staged, 2-buf counted-vmcnt + cvt_adj tail ==========
// R17-proven config: grid (157, FSPLIT=16, 2); LDS 2 x 12KB; waits 3/0; 2-row cvt tail.
__global__ __launch_bounds__(256) void gmmf_kernel(
    const float* __restrict__ A0, const float* __restrict__ A1,
    const unsigned short* __restrict__ BT, float* __restrict__ out,
    const float* __restrict__ comb,
    const float* __restrict__ adj, unsigned short* __restrict__ adjb) {
  __shared__ unsigned char lds[2][12288];  // [buf][A f32 8KB | B bf16 4KB]
  const int tid = threadIdx.x, wv = tid >> 6, lane = tid & 63;
  const int lr = lane & 15, lg = lane >> 4;
  const int r0 = blockIdx.x * 64;
  const int s0 = blockIdx.y * FSTEPS;
  const float* A = blockIdx.z ? A1 : A0;
  int cm[4], cn[4];
  calib_mn(lane, cm, cn);

  f32x4 acc[4];
#pragma unroll
  for (int t = 0; t < 4; ++t)
#pragma unroll
    for (int j = 0; j < 4; ++j) acc[t][j] = 0.f;

  const size_t alim = (size_t)NN * NN - 4;

  auto stage = [&](int b, int s) {
    const int k0 = s * 32;
#pragma unroll
    for (int i = 0; i < 2; ++i) {  // A f32: 512 units (8/row), chunk = slot ^ (row&7)
      const int U = i * 256 + wv * 64 + lane;
      const int row = U >> 3, slot = U & 7;
      const int chunk = slot ^ (row & 7);
      const int gr = (r0 + row < NN) ? (r0 + row) : (NN - 1);
      size_t off = (size_t)gr * NN + k0 + chunk * 4;
      if (off > alim) off = alim;  // k-pad clamp; B pad zeros kill the product
      __builtin_amdgcn_global_load_lds(A + off,
                                       (void*)&lds[b][(i * 256 + wv * 64) * 16], 16, 0, 0);
    }
    {  // B bf16: 256 units (4/col), chunk = slot ^ ((col>>1)&3)
      const int V = wv * 64 + lane;
      const int col = V >> 2, slot = V & 3;
      const int chunk = slot ^ ((col >> 1) & 3);
      __builtin_amdgcn_global_load_lds(BT + (size_t)col * STRD + k0 + chunk * 8,
                                       (void*)&lds[b][8192 + wv * 1024], 16, 0, 0);
    }
  };

  stage(0, s0); stage(1, s0 + 1);

  int bi = 0;
  for (int u = 0; u < FSTEPS; ++u) {
    if (u + 1 < FSTEPS) vmwait(3);
    else                vmwait(0);
    __builtin_amdgcn_sched_barrier(0);
    __builtin_amdgcn_s_barrier();
    FENCE_ANCHOR();
    {
      const unsigned char* L = lds[bi];
      const int row = wv * 16 + lr;
      s16x8 af;
#pragma unroll
      for (int d = 0; d < 2; ++d) {
        const int c = 2 * lg + d;
        const int chunk = c ^ (row & 7);
        const float4 f = *(const float4*)(L + row * 128 + (chunk << 4));
        af[4 * d + 0] = (short)f2bf(f.x);
        af[4 * d + 1] = (short)f2bf(f.y);
        af[4 * d + 2] = (short)f2bf(f.z);
        af[4 * d + 3] = (short)f2bf(f.w);
      }
#pragma unroll
      for (int t = 0; t < 4; ++t) {
        const int col = t * 16 + lr;
        const s16x8 bf = *(const s16x8*)(L + 8192 + col * 64 + ((lg ^ ((col >> 1) & 3)) << 4));
        MFMA16(acc[t], af, bf);
      }
    }
    asm volatile("s_waitcnt lgkmcnt(0)" ::: "memory");
    __builtin_amdgcn_sched_barrier(0);
    __builtin_amdgcn_s_barrier();
    FENCE_ANCHOR();
    if (u + 2 < FSTEPS) stage(bi, s0 + u + 2);
    bi ^= 1;
  }

#pragma unroll
  for (int t = 0; t < 4; ++t) {
#pragma unroll
    for (int q = 0; q < 4; ++q) {
      const int c = 16 * t + cn[q];
      const int r = r0 + wv * 16 + cm[q];
      if (r < NN)
        atomicAdd(&out[(size_t)r * NCLS + c], comb[blockIdx.z * NCLS + c] * acc[t][q]);
    }
  }

  // ---- fused cvt_adj tail: this block converts 2 rows of adj -> adjb ----
  const int gid = blockIdx.x + 157 * (blockIdx.y + FSPLIT * blockIdx.z);
#pragma unroll
  for (int h = 0; h < 2; ++h) {
    const int row = gid * 2 + h;
    if (row < NN) {
      const float* src = adj + (size_t)row * NN;
      unsigned short* dst = adjb + (size_t)row * STRD;
      for (int c = tid * 8; c < NN; c += 2048) {
        const float4 fa = *(const float4*)(src + c);
        const float4 fb = *(const float4*)(src + c + 4);
        s16x8 r;
        r[0] = (short)f2bf(fa.x); r[1] = (short)f2bf(fa.y);
        r[2] = (short)f2bf(fa.z); r[3] = (short)f2bf(fa.w);
        r[4] = (short)f2bf(fb.x); r[5] = (short)f2bf(fb.y);
        r[6] = (short)f2bf(fb.z); r[7] = (short)f2bf(fb.w);
        *(s16x8*)(dst + c) = r;
      }
      for (int c = NN + tid; c < STRD; c += 256) dst[c] = 0;
    }
  }
}

// ---------------- finish: out += comb*Yf, PT = bf16(Yf^T) (if PT), Yf = 0 ----------------
__global__ __launch_bounds__(256) void finish_old_kernel(
    float* __restrict__ Yf, const float* __restrict__ comb, int didx,
    unsigned short* __restrict__ PT, float* __restrict__ out) {
  __shared__ float ysh[32][65];
  const int tid = threadIdx.x;
  const int r0 = blockIdx.x * 32;
#pragma unroll
  for (int j = 0; j < 8; ++j) {
    const int idx = j * 256 + tid;
    const int rr = idx >> 6;
    const int c = idx & 63;
    const int r = r0 + rr;
    if (r < NN) {
      const float y = Yf[(size_t)r * NCLS + c];
      Yf[(size_t)r * NCLS + c] = 0.f;
      ysh[rr][c] = y;
      out[(size_t)r * NCLS + c] += comb[didx * NCLS + c] * y;
    }
  }
  if (!PT) return;  // last power pass: p10 never consumed
  __syncthreads();
  const int c = tid >> 2;
  const int rr = (tid & 3) * 8;
  if (r0 + rr + 7 < NN) {
    ushort4 u0 = make_ushort4(f2bf(ysh[rr + 0][c]), f2bf(ysh[rr + 1][c]),
                              f2bf(ysh[rr + 2][c]), f2bf(ysh[rr + 3][c]));
    ushort4 u1 = make_ushort4(f2bf(ysh[rr + 4][c]), f2bf(ysh[rr + 5][c]),
                              f2bf(ysh[rr + 6][c]), f2bf(ysh[rr + 7][c]));
    *(ushort4*)(PT + (size_t)c * STRD + r0 + rr) = u0;
    *(ushort4*)(PT + (size_t)c * STRD + r0 + rr + 4) = u1;
  }
}

extern "C" void kernel_launch(void* const* d_in, const int* in_sizes, int n_in,
                              void* d_out, int out_size, void* d_ws, size_t ws_size,
                              hipStream_t stream) {
  const float* x = (const float*)d_in[0];
  const float* adj = (const float*)d_in[1];
  const float* filt0 = (const float*)d_in[2];
  const float* filt1 = (const float*)d_in[3];
  const float* W1 = (const float*)d_in[4];
  const float* b1 = (const float*)d_in[5];
  const float* W2 = (const float*)d_in[6];
  const float* b2 = (const float*)d_in[7];
  const float* comb = (const float*)d_in[8];
  float* out = (float*)d_out;

  unsigned char* wsb = (unsigned char*)d_ws;
  size_t off = 0;
  auto carve = [&](size_t bytes) -> void* {
    void* p = wsb + off;
    off += (bytes + 255) & ~(size_t)255;
    return p;
  };
  unsigned short* W1T = (unsigned short*)carve((size_t)FEAT * HID * 2);
  unsigned short* W2T = (unsigned short*)carve((size_t)HID * NCLS * 2);
  unsigned short* H1 = (unsigned short*)carve((size_t)NN * HID * 2);
  float* Yf = (float*)carve((size_t)NN * NCLS * 4);
  unsigned short* HT = (unsigned short*)carve((size_t)NCLS * STRD * 2);
  unsigned short* pA = (unsigned short*)carve((size_t)NCLS * STRD * 2);
  unsigned short* pB = (unsigned short*)carve((size_t)NCLS * STRD * 2);
  unsigned short* adjb = (unsigned short*)carve((size_t)NN * STRD * 2);

  if (ws_size < off) {
    // Sentinel: absmax == 5.40625 exactly => ws too small.
    zero_f32_kernel<<<(out_size + 255) / 256, 256, 0, stream>>>(out, out_size);
    return;
  }

  zero_f32_kernel<<<(NN * NCLS + 255) / 256, 256, 0, stream>>>(Yf, NN * NCLS);
  prep_kernel<<<(FEAT * HID + 255) / 256, 256, 0, stream>>>(W1, W2, W1T, W2T, HT, pA, pB);
  mlp1_kernel<<<(NN + 15) / 16, 256, 0, stream>>>(x, W1T, b1, H1);
  mlp2_kernel<<<(NN + 15) / 16, 256, 0, stream>>>(H1, W2T, b2, comb, HT, out);

  // filters (scaled atomics into out) + fused adj->adjb conversion tail
  gmmf_kernel<<<dim3(157, FSPLIT, 2), 256, 0, stream>>>(
      filt0, filt1, HT, out, comb, adj, adjb);

  const unsigned short* pin = HT;
  for (int k = 1; k <= 10; ++k) {
    unsigned short* pout = (k & 1) ? pA : pB;
    gmm2_kernel<<<dim3(79, PSPLIT), 256, 0, stream>>>(adjb, pin, Yf);
    finish_old_kernel<<<313, 256, 0, stream>>>(
        Yf, comb, 2 + k, (k == 10) ? nullptr : pout, out);
    pin = pout;
  }
}

// Round 20
// 888.170 us; speedup vs baseline: 1.0738x; 1.0738x over previous
//
#include <hip/hip_runtime.h>

#define NN 10000
#define STRD 10272   // bf16 panel/adjb row stride (elements)
#define FSPLIT 16    // gmmf K-slices
#define FSTEPS 20    // gmmf K-steps of 32
#define PSPLIT 8     // gmm2 K-slices
#define PSTEPS 40    // gmm2 K-steps of 32 (8*40*32 = 10240 padded)
#define FEAT 2048
#define HID 128
#define NCLS 64

typedef short s16x8 __attribute__((ext_vector_type(8)));
typedef float f32x4 __attribute__((ext_vector_type(4)));

static __device__ __forceinline__ unsigned short f2bf(float f) {
  unsigned int u = __float_as_uint(f);
  u += 0x7FFFu + ((u >> 16) & 1u);
  return (unsigned short)(u >> 16);
}

#define MFMA16(accv, av, bv) \
  (accv) = __builtin_amdgcn_mfma_f32_16x16x32_bf16((av), (bv), (accv), 0, 0, 0)

#define FENCE_ANCHOR() do { asm volatile("" ::: "memory"); __builtin_amdgcn_sched_barrier(0); } while (0)

__device__ __forceinline__ void vmwait(int n) {
  switch (n) {
    case 0: asm volatile("s_waitcnt vmcnt(0)" ::: "memory"); break;
    case 2: asm volatile("s_waitcnt vmcnt(2)" ::: "memory"); break;
    case 3: asm volatile("s_waitcnt vmcnt(3)" ::: "memory"); break;
    case 4: asm volatile("s_waitcnt vmcnt(4)" ::: "memory"); break;
    case 5: asm volatile("s_waitcnt vmcnt(5)" ::: "memory"); break;
    default: asm volatile("s_waitcnt vmcnt(6)" ::: "memory"); break;
  }
}

// Self-calibration of the MFMA C/D lane->(m,n) mapping (proved correct in R2).
__device__ __forceinline__ void calib_mn(int lane, int* cm, int* cn) {
  const int lr = lane & 15;
  const int lg = lane >> 4;
  s16x8 pa, pb;
#pragma unroll
  for (int j = 0; j < 8; ++j) { pa[j] = 0; pb[j] = 0; }
  if (lg == 0) {
    pa[0] = (short)f2bf(1.0f);
    pa[1] = (short)f2bf((float)(1 + lr));
    pb[0] = (short)f2bf((float)(128 * (1 + lr)));
    pb[1] = (short)f2bf(1.0f);
  }
  f32x4 acc;
#pragma unroll
  for (int j = 0; j < 4; ++j) acc[j] = 0.f;
  MFMA16(acc, pa, pb);
#pragma unroll
  for (int r = 0; r < 4; ++r) {
    const int v = (int)acc[r];
    cm[r] = (v & 127) - 1;
    cn[r] = (v >> 7) - 1;
  }
}

__global__ void zero_f32_kernel(float* __restrict__ p, int n) {
  int i = blockIdx.x * 256 + threadIdx.x;
  if (i < n) p[i] = 0.f;
}

// prep: transpose W1, W2 to bf16; zero pad columns of the 3 bf16 p-panels
__global__ void prep_kernel(const float* __restrict__ W1, const float* __restrict__ W2,
                            unsigned short* __restrict__ W1T, unsigned short* __restrict__ W2T,
                            unsigned short* __restrict__ HT, unsigned short* __restrict__ pA,
                            unsigned short* __restrict__ pB) {
  const int idx = blockIdx.x * 256 + threadIdx.x;
  if (idx < FEAT * HID) {
    const int k = idx / HID, c = idx % HID;
    W1T[(size_t)c * FEAT + k] = f2bf(W1[idx]);
  }
  if (idx < HID * NCLS) {
    const int k = idx / NCLS, c = idx % NCLS;
    W2T[(size_t)c * HID + k] = f2bf(W2[idx]);
  }
  if (idx < 3 * 64 * (STRD - NN)) {
    const int span = 64 * (STRD - NN);
    const int p = idx / span;
    const int rem = idx % span;
    const int c = rem / (STRD - NN);
    const int col = NN + rem % (STRD - NN);
    unsigned short* pan = (p == 0) ? HT : ((p == 1) ? pA : pB);
    pan[(size_t)c * STRD + col] = 0;
  }
}

// ---------------- MLP layer 1 ----------------
__global__ __launch_bounds__(256) void mlp1_kernel(
    const float* __restrict__ X, const unsigned short* __restrict__ W1T,
    const float* __restrict__ b1, unsigned short* __restrict__ H1) {
  __shared__ float red[4][16][HID];
  const int tid = threadIdx.x, wv = tid >> 6, lane = tid & 63;
  const int lr = lane & 15, lg = lane >> 4;
  const int r0 = blockIdx.x * 16;
  int cm[4], cn[4];
  calib_mn(lane, cm, cn);

  f32x4 acc[8];
#pragma unroll
  for (int t = 0; t < 8; ++t)
#pragma unroll
    for (int j = 0; j < 4; ++j) acc[t][j] = 0.f;

  for (int s = wv * 16; s < wv * 16 + 16; ++s) {
    const int kg = s * 32 + 8 * lg;
    const float* px = X + (size_t)(r0 + lr) * FEAT + kg;
    const float4 xa = *(const float4*)(px);
    const float4 xb = *(const float4*)(px + 4);
    s16x8 af;
    af[0] = (short)f2bf(xa.x); af[1] = (short)f2bf(xa.y);
    af[2] = (short)f2bf(xa.z); af[3] = (short)f2bf(xa.w);
    af[4] = (short)f2bf(xb.x); af[5] = (short)f2bf(xb.y);
    af[6] = (short)f2bf(xb.z); af[7] = (short)f2bf(xb.w);
#pragma unroll
    for (int t = 0; t < 8; ++t) {
      const s16x8 bf = *(const s16x8*)(W1T + (size_t)(16 * t + lr) * FEAT + kg);
      MFMA16(acc[t], af, bf);
    }
  }
#pragma unroll
  for (int t = 0; t < 8; ++t)
#pragma unroll
    for (int r = 0; r < 4; ++r)
      red[wv][cm[r]][16 * t + cn[r]] = acc[t][r];
  __syncthreads();

  const int row = tid >> 4;
  const int c0 = (tid & 15) * 8;
  s16x8 hv;
#pragma unroll
  for (int j = 0; j < 8; ++j) {
    float v = red[0][row][c0 + j] + red[1][row][c0 + j] +
              red[2][row][c0 + j] + red[3][row][c0 + j] + b1[c0 + j];
    v = fmaxf(v, 0.f);
    hv[j] = (short)f2bf(v);
  }
  *(s16x8*)(H1 + (size_t)(r0 + row) * HID + c0) = hv;
}

// ---------------- MLP layer 2 -> HT (bf16 64 x STRD) + out init ----------------
__global__ __launch_bounds__(256) void mlp2_kernel(
    const unsigned short* __restrict__ H1, const unsigned short* __restrict__ W2T,
    const float* __restrict__ b2, const float* __restrict__ comb,
    unsigned short* __restrict__ HT, float* __restrict__ out) {
  __shared__ float red[4][16][NCLS];
  const int tid = threadIdx.x, wv = tid >> 6, lane = tid & 63;
  const int lr = lane & 15, lg = lane >> 4;
  const int r0 = blockIdx.x * 16;
  int cm[4], cn[4];
  calib_mn(lane, cm, cn);

  f32x4 acc[4];
#pragma unroll
  for (int t = 0; t < 4; ++t)
#pragma unroll
    for (int j = 0; j < 4; ++j) acc[t][j] = 0.f;

  const int kg = wv * 32 + 8 * lg;
  const s16x8 af = *(const s16x8*)(H1 + (size_t)(r0 + lr) * HID + kg);
#pragma unroll
  for (int t = 0; t < 4; ++t) {
    const s16x8 bf = *(const s16x8*)(W2T + (size_t)(16 * t + lr) * HID + kg);
    MFMA16(acc[t], af, bf);
  }
#pragma unroll
  for (int t = 0; t < 4; ++t)
#pragma unroll
    for (int r = 0; r < 4; ++r)
      red[wv][cm[r]][16 * t + cn[r]] = acc[t][r];
  __syncthreads();

  const int row = tid >> 4;
  const int c4 = (tid & 15) * 4;
#pragma unroll
  for (int j = 0; j < 4; ++j) {
    const int c = c4 + j;
    const float v = red[0][row][c] + red[1][row][c] + red[2][row][c] + red[3][row][c] + b2[c];
    out[(size_t)(r0 + row) * NCLS + c] = comb[2 * NCLS + c] * v;
    HT[(size_t)c * STRD + r0 + row] = f2bf(v);
  }
}

// ================ gmm2: bf16 power pass — M=64, 3-buf counted-vmcnt (R17-proven) ============
// grid (157, PSPLIT=8): 40 K-steps per block. LDS 3 x 8KB. Swizzle f(x) = (x>>1)&3.
__global__ __launch_bounds__(256) void gmm2_kernel(
    const unsigned short* __restrict__ Ab, const unsigned short* __restrict__ BT,
    float* __restrict__ Yf) {
  __shared__ unsigned char lds[3][8192];
  const int tid = threadIdx.x, wv = tid >> 6, lane = tid & 63;
  const int lr = lane & 15, lg = lane >> 4;
  const int r0 = blockIdx.x * 64;
  const int s0 = blockIdx.y * PSTEPS;
  int cm[4], cn[4];
  calib_mn(lane, cm, cn);

  f32x4 acc[4];
#pragma unroll
  for (int t = 0; t < 4; ++t)
#pragma unroll
    for (int j = 0; j < 4; ++j) acc[t][j] = 0.f;

  auto stage = [&](int b, int s) {
    const int k0 = s * 32;
    {  // A: 256 16B-units (4/row)
      const int U = wv * 64 + lane;
      const int row = U >> 2, slot = U & 3;
      const int chunk = slot ^ ((row >> 1) & 3);
      const int gr = (r0 + row < NN) ? (r0 + row) : (NN - 1);
      __builtin_amdgcn_global_load_lds(Ab + (size_t)gr * STRD + k0 + chunk * 8,
                                       (void*)&lds[b][wv * 1024], 16, 0, 0);
    }
    {  // B: 256 16B-units (4/col)
      const int V = wv * 64 + lane;
      const int col = V >> 2, slot = V & 3;
      const int chunk = slot ^ ((col >> 1) & 3);
      __builtin_amdgcn_global_load_lds(BT + (size_t)col * STRD + k0 + chunk * 8,
                                       (void*)&lds[b][4096 + wv * 1024], 16, 0, 0);
    }
  };

  stage(0, s0); stage(1, s0 + 1); stage(2, s0 + 2);

  int bi = 0;
  for (int u = 0; u < PSTEPS; ++u) {
    if (u + 2 < PSTEPS)      vmwait(4);
    else if (u + 1 < PSTEPS) vmwait(2);
    else                     vmwait(0);
    __builtin_amdgcn_sched_barrier(0);
    __builtin_amdgcn_s_barrier();  // all waves' stage-u DMA landed
    FENCE_ANCHOR();
    {
      const unsigned char* L = lds[bi];
      const int row = wv * 16 + lr;
      const s16x8 af = *(const s16x8*)(L + row * 64 + ((lg ^ ((row >> 1) & 3)) << 4));
#pragma unroll
      for (int t = 0; t < 4; ++t) {
        const int col = t * 16 + lr;
        const s16x8 bf = *(const s16x8*)(L + 4096 + col * 64 + ((lg ^ ((col >> 1) & 3)) << 4));
        MFMA16(acc[t], af, bf);
      }
    }
    asm volatile("s_waitcnt lgkmcnt(0)" ::: "memory");  // my ds_reads done
    __builtin_amdgcn_sched_barrier(0);
    __builtin_amdgcn_s_barrier();  // all waves done reading buf bi
    FENCE_ANCHOR();
    if (u + 3 < PSTEPS) stage(bi, s0 + u + 3);  // loads fly across barriers
    bi = (bi == 2) ? 0 : bi + 1;
  }

#pragma unroll
  for (int t = 0; t < 4; ++t) {
#pragma unroll
    for (int q = 0; q < 4; ++q) {
      const int c = 16 * t + cn[q];
      const int r = r0 + wv * 16 + cm[q];
      if (r < NN) atomicAdd(&Yf[(size_t)r * NCLS + c], acc[t][q]);
    }
  }
}

// ================ gmmf: filters — f32 A staged, 2-buf counted-vmcnt + cvt_adj tail ==========
// R17-proven config: grid (157, FSPLIT=16, 2); LDS 2 x 12KB; waits 3/0; 2-row cvt tail.
__global__ __launch_bounds__(256) void gmmf_kernel(
    const float* __restrict__ A0, const float* __restrict__ A1,
    const unsigned short* __restrict__ BT, float* __restrict__ out,
    const float* __restrict__ comb,
    const float* __restrict__ adj, unsigned short* __restrict__ adjb) {
  __shared__ unsigned char lds[2][12288];  // [buf][A f32 8KB | B bf16 4KB]
  const int tid = threadIdx.x, wv = tid >> 6, lane = tid & 63;
  const int lr = lane & 15, lg = lane >> 4;
  const int r0 = blockIdx.x * 64;
  const int s0 = blockIdx.y * FSTEPS;
  const float* A = blockIdx.z ? A1 : A0;
  int cm[4], cn[4];
  calib_mn(lane, cm, cn);

  f32x4 acc[4];
#pragma unroll
  for (int t = 0; t < 4; ++t)
#pragma unroll
    for (int j = 0; j < 4; ++j) acc[t][j] = 0.f;

  const size_t alim = (size_t)NN * NN - 4;

  auto stage = [&](int b, int s) {
    const int k0 = s * 32;
#pragma unroll
    for (int i = 0; i < 2; ++i) {  // A f32: 512 units (8/row), chunk = slot ^ (row&7)
      const int U = i * 256 + wv * 64 + lane;
      const int row = U >> 3, slot = U & 7;
      const int chunk = slot ^ (row & 7);
      const int gr = (r0 + row < NN) ? (r0 + row) : (NN - 1);
      size_t off = (size_t)gr * NN + k0 + chunk * 4;
      if (off > alim) off = alim;  // k-pad clamp; B pad zeros kill the product
      __builtin_amdgcn_global_load_lds(A + off,
                                       (void*)&lds[b][(i * 256 + wv * 64) * 16], 16, 0, 0);
    }
    {  // B bf16: 256 units (4/col), chunk = slot ^ ((col>>1)&3)
      const int V = wv * 64 + lane;
      const int col = V >> 2, slot = V & 3;
      const int chunk = slot ^ ((col >> 1) & 3);
      __builtin_amdgcn_global_load_lds(BT + (size_t)col * STRD + k0 + chunk * 8,
                                       (void*)&lds[b][8192 + wv * 1024], 16, 0, 0);
    }
  };

  stage(0, s0); stage(1, s0 + 1);

  int bi = 0;
  for (int u = 0; u < FSTEPS; ++u) {
    if (u + 1 < FSTEPS) vmwait(3);
    else                vmwait(0);
    __builtin_amdgcn_sched_barrier(0);
    __builtin_amdgcn_s_barrier();
    FENCE_ANCHOR();
    {
      const unsigned char* L = lds[bi];
      const int row = wv * 16 + lr;
      s16x8 af;
#pragma unroll
      for (int d = 0; d < 2; ++d) {
        const int c = 2 * lg + d;
        const int chunk = c ^ (row & 7);
        const float4 f = *(const float4*)(L + row * 128 + (chunk << 4));
        af[4 * d + 0] = (short)f2bf(f.x);
        af[4 * d + 1] = (short)f2bf(f.y);
        af[4 * d + 2] = (short)f2bf(f.z);
        af[4 * d + 3] = (short)f2bf(f.w);
      }
#pragma unroll
      for (int t = 0; t < 4; ++t) {
        const int col = t * 16 + lr;
        const s16x8 bf = *(const s16x8*)(L + 8192 + col * 64 + ((lg ^ ((col >> 1) & 3)) << 4));
        MFMA16(acc[t], af, bf);
      }
    }
    asm volatile("s_waitcnt lgkmcnt(0)" ::: "memory");
    __builtin_amdgcn_sched_barrier(0);
    __builtin_amdgcn_s_barrier();
    FENCE_ANCHOR();
    if (u + 2 < FSTEPS) stage(bi, s0 + u + 2);
    bi ^= 1;
  }

#pragma unroll
  for (int t = 0; t < 4; ++t) {
#pragma unroll
    for (int q = 0; q < 4; ++q) {
      const int c = 16 * t + cn[q];
      const int r = r0 + wv * 16 + cm[q];
      if (r < NN)
        atomicAdd(&out[(size_t)r * NCLS + c], comb[blockIdx.z * NCLS + c] * acc[t][q]);
    }
  }

  // ---- fused cvt_adj tail: this block converts 2 rows of adj -> adjb ----
  const int gid = blockIdx.x + 157 * (blockIdx.y + FSPLIT * blockIdx.z);
#pragma unroll
  for (int h = 0; h < 2; ++h) {
    const int row = gid * 2 + h;
    if (row < NN) {
      const float* src = adj + (size_t)row * NN;
      unsigned short* dst = adjb + (size_t)row * STRD;
      for (int c = tid * 8; c < NN; c += 2048) {
        const float4 fa = *(const float4*)(src + c);
        const float4 fb = *(const float4*)(src + c + 4);
        s16x8 r;
        r[0] = (short)f2bf(fa.x); r[1] = (short)f2bf(fa.y);
        r[2] = (short)f2bf(fa.z); r[3] = (short)f2bf(fa.w);
        r[4] = (short)f2bf(fb.x); r[5] = (short)f2bf(fb.y);
        r[6] = (short)f2bf(fb.z); r[7] = (short)f2bf(fb.w);
        *(s16x8*)(dst + c) = r;
      }
      for (int c = NN + tid; c < STRD; c += 256) dst[c] = 0;
    }
  }
}

// ---------------- finish: out += comb*Yf, PT = bf16(Yf^T) (if PT), Yf = 0 ----------------
__global__ __launch_bounds__(256) void finish_old_kernel(
    float* __restrict__ Yf, const float* __restrict__ comb, int didx,
    unsigned short* __restrict__ PT, float* __restrict__ out) {
  __shared__ float ysh[32][65];
  const int tid = threadIdx.x;
  const int r0 = blockIdx.x * 32;
#pragma unroll
  for (int j = 0; j < 8; ++j) {
    const int idx = j * 256 + tid;
    const int rr = idx >> 6;
    const int c = idx & 63;
    const int r = r0 + rr;
    if (r < NN) {
      const float y = Yf[(size_t)r * NCLS + c];
      Yf[(size_t)r * NCLS + c] = 0.f;
      ysh[rr][c] = y;
      out[(size_t)r * NCLS + c] += comb[didx * NCLS + c] * y;
    }
  }
  if (!PT) return;  // last power pass: p10 never consumed
  __syncthreads();
  const int c = tid >> 2;
  const int rr = (tid & 3) * 8;
  if (r0 + rr + 7 < NN) {
    ushort4 u0 = make_ushort4(f2bf(ysh[rr + 0][c]), f2bf(ysh[rr + 1][c]),
                              f2bf(ysh[rr + 2][c]), f2bf(ysh[rr + 3][c]));
    ushort4 u1 = make_ushort4(f2bf(ysh[rr + 4][c]), f2bf(ysh[rr + 5][c]),
                              f2bf(ysh[rr + 6][c]), f2bf(ysh[rr + 7][c]));
    *(ushort4*)(PT + (size_t)c * STRD + r0 + rr) = u0;
    *(ushort4*)(PT + (size_t)c * STRD + r0 + rr + 4) = u1;
  }
}

extern "C" void kernel_launch(void* const* d_in, const int* in_sizes, int n_in,
                              void* d_out, int out_size, void* d_ws, size_t ws_size,
                              hipStream_t stream) {
  const float* x = (const float*)d_in[0];
  const float* adj = (const float*)d_in[1];
  const float* filt0 = (const float*)d_in[2];
  const float* filt1 = (const float*)d_in[3];
  const float* W1 = (const float*)d_in[4];
  const float* b1 = (const float*)d_in[5];
  const float* W2 = (const float*)d_in[6];
  const float* b2 = (const float*)d_in[7];
  const float* comb = (const float*)d_in[8];
  float* out = (float*)d_out;

  unsigned char* wsb = (unsigned char*)d_ws;
  size_t off = 0;
  auto carve = [&](size_t bytes) -> void* {
    void* p = wsb + off;
    off += (bytes + 255) & ~(size_t)255;
    return p;
  };
  unsigned short* W1T = (unsigned short*)carve((size_t)FEAT * HID * 2);
  unsigned short* W2T = (unsigned short*)carve((size_t)HID * NCLS * 2);
  unsigned short* H1 = (unsigned short*)carve((size_t)NN * HID * 2);
  float* Yf = (float*)carve((size_t)NN * NCLS * 4);
  unsigned short* HT = (unsigned short*)carve((size_t)NCLS * STRD * 2);
  unsigned short* pA = (unsigned short*)carve((size_t)NCLS * STRD * 2);
  unsigned short* pB = (unsigned short*)carve((size_t)NCLS * STRD * 2);
  unsigned short* adjb = (unsigned short*)carve((size_t)NN * STRD * 2);

  if (ws_size < off) {
    // Sentinel: absmax == 5.40625 exactly => ws too small.
    zero_f32_kernel<<<(out_size + 255) / 256, 256, 0, stream>>>(out, out_size);
    return;
  }

  zero_f32_kernel<<<(NN * NCLS + 255) / 256, 256, 0, stream>>>(Yf, NN * NCLS);
  prep_kernel<<<(FEAT * HID + 255) / 256, 256, 0, stream>>>(W1, W2, W1T, W2T, HT, pA, pB);
  mlp1_kernel<<<(NN + 15) / 16, 256, 0, stream>>>(x, W1T, b1, H1);
  mlp2_kernel<<<(NN + 15) / 16, 256, 0, stream>>>(H1, W2T, b2, comb, HT, out);

  // filters (scaled atomics into out) + fused adj->adjb conversion tail
  gmmf_kernel<<<dim3(157, FSPLIT, 2), 256, 0, stream>>>(
      filt0, filt1, HT, out, comb, adj, adjb);

  const unsigned short* pin = HT;
  for (int k = 1; k <= 10; ++k) {
    unsigned short* pout = (k & 1) ? pA : pB;
    gmm2_kernel<<<dim3(157, PSPLIT), 256, 0, stream>>>(adjb, pin, Yf);
    finish_old_kernel<<<313, 256, 0, stream>>>(
        Yf, comb, 2 + k, (k == 10) ? nullptr : pout, out);
    pin = pout;
  }
}